// Round 1
// baseline (936.182 us; speedup 1.0000x reference)
//
#include <hip/hip_runtime.h>
#include <stdint.h>

// ---------------------------------------------------------------------------
// WindowAttention: B_=2048 windows, N=49 tokens, C=384, H=12 heads, hd=32.
// Pipeline: prep (weights->bf16, rel-bias expand) -> fused QKV proj GEMM ->
// per-window attention (MFMA 16x16x32 bf16) -> output proj GEMM.
// ---------------------------------------------------------------------------

typedef __bf16 bf16x8 __attribute__((ext_vector_type(8)));
typedef float f32x4 __attribute__((ext_vector_type(4)));
typedef unsigned int u32x4 __attribute__((ext_vector_type(4)));
typedef unsigned int u32x2 __attribute__((ext_vector_type(2)));
typedef unsigned short u16x8 __attribute__((ext_vector_type(8)));

union Frag { u32x4 u; u16x8 s; bf16x8 v; };

// ws layout (bytes)
static constexpr size_t OFF_WQ  = 0;                       // 384*384 bf16
static constexpr size_t OFF_WK  = 294912;
static constexpr size_t OFF_WV  = 589824;
static constexpr size_t OFF_WP  = 884736;
static constexpr size_t OFF_REL = 1179648;                 // 12*49*49 f32
static constexpr size_t OFF_QH  = 1310720;                 // [2048][12][49][32] bf16
static constexpr size_t SZ_HB   = 77070336;
static constexpr size_t OFF_KH  = OFF_QH + SZ_HB;
static constexpr size_t OFF_VH  = OFF_KH + SZ_HB;
static constexpr size_t OFF_XH  = OFF_VH + SZ_HB;          // [100352][384] bf16
// total = 309,592,064 bytes

__device__ __forceinline__ unsigned short f2bf(float f){
  unsigned int u = __float_as_uint(f);
  u += 0x7FFFu + ((u >> 16) & 1u);   // round-to-nearest-even
  return (unsigned short)(u >> 16);
}

// ---------------------------------------------------------------------------
__global__ void prep_kernel(const float* __restrict__ Wq, const float* __restrict__ Wk,
                            const float* __restrict__ Wv, const float* __restrict__ Wp,
                            const float* __restrict__ btab, unsigned char* __restrict__ ws){
  unsigned short* wq = (unsigned short*)(ws + OFF_WQ);
  unsigned short* wk = (unsigned short*)(ws + OFF_WK);
  unsigned short* wv = (unsigned short*)(ws + OFF_WV);
  unsigned short* wp = (unsigned short*)(ws + OFF_WP);
  float* rel = (float*)(ws + OFF_REL);
  int tid = blockIdx.x * blockDim.x + threadIdx.x;
  int stride = gridDim.x * blockDim.x;
  for (int i = tid; i < 147456; i += stride){
    wq[i] = f2bf(Wq[i]); wk[i] = f2bf(Wk[i]); wv[i] = f2bf(Wv[i]); wp[i] = f2bf(Wp[i]);
  }
  for (int i = tid; i < 28812; i += stride){          // 12*2401
    int h = i / 2401; int r = i % 2401; int n = r / 49; int m = r % 49;
    int cn = 13 * (n / 7) + (n % 7);
    int mm = 48 - m;
    int cm = 13 * (mm / 7) + (mm % 7);
    rel[i] = btab[(cn + cm) * 12 + h];
  }
}

// ---------------------------------------------------------------------------
// QKV projection: Y = X @ W^T + bias (then *scale for q), output [B][H][49][32] bf16.
// Block: 128 rows x 384 cols, 12 waves (2x6 of 64x64), K=384 in BK=64 steps.
__global__ void __launch_bounds__(768,3) qkv_proj(const float* __restrict__ q, const float* __restrict__ k,
    const float* __restrict__ v, const float* __restrict__ bq, const float* __restrict__ bk,
    const float* __restrict__ bv, unsigned char* __restrict__ ws){
  __shared__ __attribute__((aligned(16))) unsigned short Alds[128*72]; // +8 pad: 2-way banks
  int mat = blockIdx.y;
  const float* X    = (mat==0)? q  : (mat==1)? k  : v;
  const float* bias = (mat==0)? bq : (mat==1)? bk : bv;
  const unsigned short* WB = (const unsigned short*)(ws + ((mat==0)?OFF_WQ:(mat==1)?OFF_WK:OFF_WV));
  unsigned short* OUT = (unsigned short*)(ws + ((mat==0)?OFF_QH:(mat==1)?OFF_KH:OFF_VH));
  float scale = (mat==0) ? 0.17677669529663689f : 1.0f;   // hd^-0.5 applied after bias
  int bm = blockIdx.x;
  int tid = threadIdx.x;
  int lane = tid & 63;
  int wid = tid >> 6;
  int wm = wid / 6;          // 0..1 (64-row half)
  int wn = wid % 6;          // 0..5 (64-col strip)
  int lr = lane & 15;
  int lk = (lane >> 4) * 8;
  f32x4 zero4 = {0.f,0.f,0.f,0.f};
  f32x4 acc[4][4];
  #pragma unroll
  for (int a=0;a<4;++a){
    #pragma unroll
    for (int c=0;c<4;++c) acc[a][c] = zero4;
  }
  for (int kk = 0; kk < 384; kk += 64){
    __syncthreads();
    #pragma unroll
    for (int it = 0; it < 3; ++it){
      int i = tid + it*768;
      if (i < 2048){                               // 128 rows x 16 float4
        int r = i >> 4, c4 = i & 15;
        const float* src = X + (size_t)(bm*128 + r)*384 + kk + c4*4;
        f32x4 xv = *(const f32x4*)src;
        unsigned int p0 = (unsigned int)f2bf(xv[0]) | ((unsigned int)f2bf(xv[1]) << 16);
        unsigned int p1 = (unsigned int)f2bf(xv[2]) | ((unsigned int)f2bf(xv[3]) << 16);
        u32x2 pk = {p0, p1};
        *(u32x2*)&Alds[r*72 + c4*4] = pk;
      }
    }
    __syncthreads();
    #pragma unroll
    for (int ks = 0; ks < 2; ++ks){
      Frag a[4], b[4];
      #pragma unroll
      for (int rt=0; rt<4; ++rt)
        a[rt].u = *(const u32x4*)&Alds[(wm*64 + rt*16 + lr)*72 + ks*32 + lk];
      #pragma unroll
      for (int ct=0; ct<4; ++ct){
        int n = wn*64 + ct*16 + lr;               // B^T layout: row n of W, contiguous k
        b[ct].u = *(const u32x4*)(WB + (size_t)n*384 + kk + ks*32 + lk);
      }
      #pragma unroll
      for (int rt=0; rt<4; ++rt){
        #pragma unroll
        for (int ct=0; ct<4; ++ct)
          acc[rt][ct] = __builtin_amdgcn_mfma_f32_16x16x32_bf16(a[rt].v, b[ct].v, acc[rt][ct], 0,0,0);
      }
    }
  }
  // epilogue: bias, scale, bf16, scatter to [b][h][n][d]
  int rbase = (lane >> 4) * 4;
  #pragma unroll
  for (int ct=0; ct<4; ++ct){
    int c = wn*64 + ct*16 + lr;
    float bsv = bias[c];
    int h = c >> 5, d = c & 31;
    #pragma unroll
    for (int rt=0; rt<4; ++rt){
      #pragma unroll
      for (int j=0; j<4; ++j){
        int g = bm*128 + wm*64 + rt*16 + rbase + j;   // global token row, exact (M=784*128)
        int b_ = g / 49;
        int n = g - b_*49;
        float val = (acc[rt][ct][j] + bsv) * scale;
        OUT[(size_t)((b_*12 + h)*49 + n)*32 + d] = f2bf(val);
      }
    }
  }
}

// ---------------------------------------------------------------------------
// Attention: one block per window, 4 waves x 3 heads each.
// QK^T (K=32, 1 MFMA step), masked softmax (+rel bias), PV via LDS-transposed V.
__global__ void __launch_bounds__(256,2) attn_kernel(unsigned char* __restrict__ ws){
  __shared__ __attribute__((aligned(16))) unsigned short vhT[4][2304]; // [32][72] per wave
  __shared__ __attribute__((aligned(16))) unsigned short Pl[4][4608];  // [64][72] per wave
  const unsigned short* QH = (const unsigned short*)(ws + OFF_QH);
  const unsigned short* KH = (const unsigned short*)(ws + OFF_KH);
  const unsigned short* VH = (const unsigned short*)(ws + OFF_VH);
  const float* rel = (const float*)(ws + OFF_REL);
  unsigned short* XH = (unsigned short*)(ws + OFF_XH);
  int b = blockIdx.x;
  int tid = threadIdx.x;
  int lane = tid & 63;
  int w = tid >> 6;
  int lr = lane & 15;
  int lk = (lane >> 4) * 8;
  int rbase = (lane >> 4) * 4;
  f32x4 zero4 = {0.f,0.f,0.f,0.f};
  for (int hi = 0; hi < 3; ++hi){
    int h = w + hi*4;
    size_t hoff = ((size_t)b*12 + h) * (49*32);
    __syncthreads();   // protect LDS reuse vs previous iteration's reads
    // stage V transposed into LDS: vhT[d][m], zero-pad m in [49,64)
    {
      int m = lane;
      if (m < 49){
        const u32x4* src = (const u32x4*)(VH + hoff + m*32);
        #pragma unroll
        for (int p=0; p<4; ++p){
          Frag u; u.u = src[p];
          #pragma unroll
          for (int e=0; e<8; ++e) vhT[w][(p*8+e)*72 + m] = u.s[e];
        }
      } else {
        #pragma unroll
        for (int d2=0; d2<32; ++d2) vhT[w][d2*72 + m] = 0;
      }
    }
    // QK^T: A = qh rows, B = kh rows (both contiguous-d 16B frags from global)
    Frag aq[4], bkf[4];
    #pragma unroll
    for (int rt=0; rt<4; ++rt)
      aq[rt].u = *(const u32x4*)(QH + hoff + (size_t)(rt*16 + lr)*32 + lk);
    #pragma unroll
    for (int ct=0; ct<4; ++ct)
      bkf[ct].u = *(const u32x4*)(KH + hoff + (size_t)(ct*16 + lr)*32 + lk);
    f32x4 S[4][4];
    #pragma unroll
    for (int rt=0; rt<4; ++rt){
      #pragma unroll
      for (int ct=0; ct<4; ++ct)
        S[rt][ct] = __builtin_amdgcn_mfma_f32_16x16x32_bf16(aq[rt].v, bkf[ct].v, zero4, 0,0,0);
    }
    // masked softmax over m; row n lives in 16-lane group (lane>>4), reg j
    const float* relh = rel + h*2401;
    #pragma unroll
    for (int rt=0; rt<4; ++rt){
      #pragma unroll
      for (int j=0; j<4; ++j){
        int n = rt*16 + rbase + j;
        float lg[4];
        float mx = -1e30f;
        #pragma unroll
        for (int ct=0; ct<4; ++ct){
          int m = ct*16 + lr;
          float val = S[rt][ct][j];
          if (m < 49){
            if (n < 49) val += relh[n*49 + m];
          } else val = -1e30f;
          lg[ct] = val;
          mx = fmaxf(mx, val);
        }
        mx = fmaxf(mx, __shfl_xor(mx, 1));
        mx = fmaxf(mx, __shfl_xor(mx, 2));
        mx = fmaxf(mx, __shfl_xor(mx, 4));
        mx = fmaxf(mx, __shfl_xor(mx, 8));
        float sm = 0.f;
        #pragma unroll
        for (int ct=0; ct<4; ++ct){
          float p = __expf(lg[ct] - mx);   // masked cols -> exp(-1e30-mx) = 0
          lg[ct] = p;
          sm += p;
        }
        sm += __shfl_xor(sm, 1);
        sm += __shfl_xor(sm, 2);
        sm += __shfl_xor(sm, 4);
        sm += __shfl_xor(sm, 8);
        float inv = 1.0f / sm;
        #pragma unroll
        for (int ct=0; ct<4; ++ct){
          int m = ct*16 + lr;
          Pl[w][n*72 + m] = f2bf(lg[ct] * inv);
        }
      }
    }
    __syncthreads();   // vhT + Pl writes visible before PV reads
    // PV: x[n][d] = sum_m P[n][m] * vhT[d][m]
    f32x4 xacc[4][2];
    #pragma unroll
    for (int rt=0; rt<4; ++rt){ xacc[rt][0] = zero4; xacc[rt][1] = zero4; }
    #pragma unroll
    for (int ksv=0; ksv<2; ++ksv){
      Frag ap[4], bv2[2];
      #pragma unroll
      for (int rt=0; rt<4; ++rt)
        ap[rt].u = *(const u32x4*)&Pl[w][(rt*16 + lr)*72 + ksv*32 + lk];
      #pragma unroll
      for (int dt=0; dt<2; ++dt)
        bv2[dt].u = *(const u32x4*)&vhT[w][(dt*16 + lr)*72 + ksv*32 + lk];
      #pragma unroll
      for (int rt=0; rt<4; ++rt){
        #pragma unroll
        for (int dt=0; dt<2; ++dt)
          xacc[rt][dt] = __builtin_amdgcn_mfma_f32_16x16x32_bf16(ap[rt].v, bv2[dt].v, xacc[rt][dt], 0,0,0);
      }
    }
    // write x -> token-major [g][C] bf16
    #pragma unroll
    for (int rt=0; rt<4; ++rt){
      #pragma unroll
      for (int j=0; j<4; ++j){
        int n = rt*16 + rbase + j;
        if (n < 49){
          #pragma unroll
          for (int dt=0; dt<2; ++dt){
            XH[(size_t)(b*49 + n)*384 + h*32 + dt*16 + lr] = f2bf(xacc[rt][dt][j]);
          }
        }
      }
    }
  }
}

// ---------------------------------------------------------------------------
// Output projection: out = XH @ Wp^T + bp (fp32 out). Same tiling as qkv_proj.
__global__ void __launch_bounds__(768,3) out_proj(const float* __restrict__ bp,
    const unsigned char* __restrict__ ws, float* __restrict__ out){
  __shared__ __attribute__((aligned(16))) unsigned short Alds[128*72];
  const unsigned short* XH = (const unsigned short*)(ws + OFF_XH);
  const unsigned short* WB = (const unsigned short*)(ws + OFF_WP);
  int bm = blockIdx.x;
  int tid = threadIdx.x;
  int lane = tid & 63;
  int wid = tid >> 6;
  int wm = wid / 6;
  int wn = wid % 6;
  int lr = lane & 15;
  int lk = (lane >> 4) * 8;
  f32x4 zero4 = {0.f,0.f,0.f,0.f};
  f32x4 acc[4][4];
  #pragma unroll
  for (int a=0;a<4;++a){
    #pragma unroll
    for (int c=0;c<4;++c) acc[a][c] = zero4;
  }
  for (int kk = 0; kk < 384; kk += 64){
    __syncthreads();
    #pragma unroll
    for (int it = 0; it < 2; ++it){
      int i = tid + it*768;
      if (i < 1024){                              // 128 rows x 8 x (8 bf16)
        int r = i >> 3, c8 = i & 7;
        u32x4 t4 = *(const u32x4*)(XH + (size_t)(bm*128 + r)*384 + kk + c8*8);
        *(u32x4*)&Alds[r*72 + c8*8] = t4;
      }
    }
    __syncthreads();
    #pragma unroll
    for (int ks = 0; ks < 2; ++ks){
      Frag a[4], b[4];
      #pragma unroll
      for (int rt=0; rt<4; ++rt)
        a[rt].u = *(const u32x4*)&Alds[(wm*64 + rt*16 + lr)*72 + ks*32 + lk];
      #pragma unroll
      for (int ct=0; ct<4; ++ct){
        int n = wn*64 + ct*16 + lr;
        b[ct].u = *(const u32x4*)(WB + (size_t)n*384 + kk + ks*32 + lk);
      }
      #pragma unroll
      for (int rt=0; rt<4; ++rt){
        #pragma unroll
        for (int ct=0; ct<4; ++ct)
          acc[rt][ct] = __builtin_amdgcn_mfma_f32_16x16x32_bf16(a[rt].v, b[ct].v, acc[rt][ct], 0,0,0);
      }
    }
  }
  int rbase = (lane >> 4) * 4;
  #pragma unroll
  for (int ct=0; ct<4; ++ct){
    int c = wn*64 + ct*16 + lr;
    float bsv = bp[c];
    #pragma unroll
    for (int rt=0; rt<4; ++rt){
      #pragma unroll
      for (int j=0; j<4; ++j){
        int g = bm*128 + wm*64 + rt*16 + rbase + j;
        out[(size_t)g*384 + c] = acc[rt][ct][j] + bsv;
      }
    }
  }
}

// ---------------------------------------------------------------------------
extern "C" void kernel_launch(void* const* d_in, const int* in_sizes, int n_in,
                              void* d_out, int out_size, void* d_ws, size_t ws_size,
                              hipStream_t stream){
  const float* q  = (const float*)d_in[0];
  const float* k  = (const float*)d_in[1];
  const float* v  = (const float*)d_in[2];
  const float* Wq = (const float*)d_in[3];
  const float* bq = (const float*)d_in[4];
  const float* Wk = (const float*)d_in[5];
  const float* bk = (const float*)d_in[6];
  const float* Wv = (const float*)d_in[7];
  const float* bv = (const float*)d_in[8];
  const float* Wp = (const float*)d_in[9];
  const float* bp = (const float*)d_in[10];
  const float* bt = (const float*)d_in[11];
  unsigned char* ws = (unsigned char*)d_ws;

  prep_kernel<<<dim3(256), dim3(256), 0, stream>>>(Wq, Wk, Wv, Wp, bt, ws);
  qkv_proj<<<dim3(784,3), dim3(768), 0, stream>>>(q, k, v, bq, bk, bv, ws);
  attn_kernel<<<dim3(2048), dim3(256), 0, stream>>>(ws);
  out_proj<<<dim3(784), dim3(768), 0, stream>>>(bp, ws, (float*)d_out);
}